// Round 1
// baseline (255.706 us; speedup 1.0000x reference)
//
#include <hip/hip_runtime.h>
#include <math.h>

#define CC 64
#define RR 4
#define HH 128
#define WW 128
#define BB 8
#define LL (HH*WW)
#define COUT 128
#define TILE 32
#define NTW (WW/TILE)

__device__ __forceinline__ unsigned short f2bf(float f) {
  unsigned u = __float_as_uint(f);
  u += 0x7fffu + ((u >> 16) & 1u);
  return (unsigned short)(u >> 16);
}
__device__ __forceinline__ float bf2f(unsigned short h) {
  return __uint_as_float(((unsigned)h) << 16);
}

// --- K1: kern table (R*9 = 36 values) -> ws[0..35]
__global__ void k_kern_table(const float* __restrict__ theta,
                             const float* __restrict__ rsu,
                             const float* __restrict__ rss,
                             float* __restrict__ wkern) {
  int t = threadIdx.x;
  if (t < RR * 9) {
    int r = t / 9, s = t % 9;
    float dy = (float)(s / 3 - 1), dx = (float)(s % 3 - 1);
    float ct = cosf(theta[r]), st = sinf(theta[r]);
    float su = log1pf(expf(rsu[r])) + 1e-4f;
    float sv = log1pf(expf(rss[r])) + 1e-4f;
    float pu = ct * dx + st * dy;
    float ps = -st * dx + ct * dy;
    wkern[t] = expf(-(pu * pu) / (su * su) - (ps * ps) / (sv * sv));
  }
}

// --- K2: mu = softmax_r( x . gate_w + gate_b ), one thread per pixel
__global__ __launch_bounds__(256) void k_mu(const float* __restrict__ x,
                                            const float* __restrict__ gw,
                                            const float* __restrict__ gb,
                                            float* __restrict__ mu) {
  __shared__ float gws[RR * CC];
  int tid = threadIdx.x;
  if (tid < RR * CC) gws[tid] = gw[tid];
  __syncthreads();
  int idx = blockIdx.x * 256 + tid;       // b*L + l
  int b = idx >> 14, l = idx & (LL - 1);
  float lg0 = gb[0], lg1 = gb[1], lg2 = gb[2], lg3 = gb[3];
  const float* xp = x + (((size_t)b * CC) << 14) + l;
  #pragma unroll 8
  for (int c = 0; c < CC; ++c) {
    float xv = xp[(size_t)c << 14];
    lg0 += xv * gws[c];
    lg1 += xv * gws[CC + c];
    lg2 += xv * gws[2 * CC + c];
    lg3 += xv * gws[3 * CC + c];
  }
  float m = fmaxf(fmaxf(lg0, lg1), fmaxf(lg2, lg3));
  float e0 = expf(lg0 - m), e1 = expf(lg1 - m);
  float e2 = expf(lg2 - m), e3 = expf(lg3 - m);
  float inv = 1.0f / (e0 + e1 + e2 + e3);
  float* mp = mu + (((size_t)b * RR) << 14) + l;
  mp[0] = e0 * inv;
  mp[(size_t)1 << 14] = e1 * inv;
  mp[(size_t)2 << 14] = e2 * inv;
  mp[(size_t)3 << 14] = e3 * inv;
}

// --- K3: fused alpha -> agg -> pointwise GEMM, one block per (b, h, 32-px tile)
__global__ __launch_bounds__(256) void k_fused(const float* __restrict__ x,
                                               const float* __restrict__ mu,
                                               const float* __restrict__ wkern,
                                               const float* __restrict__ pw,
                                               const float* __restrict__ pb,
                                               float* __restrict__ out) {
  // xs: x neighborhood [c][row*35+col], cols 0..33 = w0-1..w0+32, rows h-1..h+1
  // pws reuses xs region (dead after phase C)
  __shared__ union ShU { float xs[CC * 105]; float pws[32 * 132]; } U;
  __shared__ float mus[RR * 105];
  __shared__ float alp[36][TILE + 1];
  __shared__ unsigned short aggs[TILE][266];   // bf16 agg, [pixel][rc]
  __shared__ float kl[36];

  int tid = threadIdx.x;
  int bid = blockIdx.x;
  int b = bid / (HH * NTW);
  int rem = bid % (HH * NTW);
  int h = rem / NTW;
  int w0 = (rem % NTW) * TILE;

  if (tid < 36) kl[tid] = wkern[tid];

  // phase A: stage x and mu neighborhoods (zero-padded)
  for (int i = tid; i < CC * 102; i += 256) {
    int c = i / 102, j = i % 102;
    int rr = j / 34, cc2 = j % 34;
    int row = h - 1 + rr, col = w0 - 1 + cc2;
    float v = 0.0f;
    if ((unsigned)row < HH && (unsigned)col < WW)
      v = x[(((size_t)b * CC + c) << 14) + (row << 7) + col];
    U.xs[c * 105 + rr * 35 + cc2] = v;
  }
  for (int i = tid; i < RR * 102; i += 256) {
    int r = i / 102, j = i % 102;
    int rr = j / 34, cc2 = j % 34;
    int row = h - 1 + rr, col = w0 - 1 + cc2;
    float v = 0.0f;
    if ((unsigned)row < HH && (unsigned)col < WW)
      v = mu[(((size_t)b * RR + r) << 14) + (row << 7) + col];
    mus[r * 105 + rr * 35 + cc2] = v;
  }
  __syncthreads();

  // phase B: alpha[36] per pixel, normalized over all (r,s)
  if (tid < TILE) {
    int t = tid;
    float a[36], sum = 0.0f;
    #pragma unroll
    for (int r = 0; r < RR; ++r) {
      float mc = mus[r * 105 + 35 + t + 1];   // center mu
      #pragma unroll
      for (int s = 0; s < 9; ++s) {
        float v = mc * mus[r * 105 + (s / 3) * 35 + t + (s % 3)] * kl[r * 9 + s];
        a[r * 9 + s] = v;
        sum += v;
      }
    }
    float inv = 1.0f / fmaxf(sum, 1e-8f);
    #pragma unroll
    for (int j2 = 0; j2 < 36; ++j2) alp[j2][t] = a[j2] * inv;
  }
  __syncthreads();

  // phase C: agg[rc][t] = sum_s alpha[r][s][t] * x[c][nb(t,s)], store bf16
  {
    int r = tid >> 6;
    int c = tid & 63;
    const float* xrow = &U.xs[c * 105];
    for (int t = 0; t < TILE; ++t) {
      float acc = 0.0f;
      #pragma unroll
      for (int s = 0; s < 9; ++s)
        acc += alp[r * 9 + s][t] * xrow[(s / 3) * 35 + t + (s % 3)];
      aggs[t][tid] = f2bf(acc);
    }
  }

  // phase D: out[128][32] = pw[128][256] @ agg[256][32] (+bias)
  float acc[8][2];
  #pragma unroll
  for (int j = 0; j < 8; ++j) { acc[j][0] = 0.0f; acc[j][1] = 0.0f; }
  int o0 = (tid >> 4) * 8;        // 16 o-groups of 8
  int t0 = (tid & 15) * 2;        // 16 t-groups of 2 (contiguous px per wave)

  for (int k0 = 0; k0 < 256; k0 += 32) {
    __syncthreads();              // protects U reuse + aggs readiness (1st iter)
    for (int i = tid; i < 32 * 128; i += 256) {
      int o = i >> 5, kk = i & 31;
      U.pws[kk * 132 + o] = pw[o * 256 + k0 + kk];
    }
    __syncthreads();
    #pragma unroll
    for (int kk = 0; kk < 32; kk += 4) {
      ushort4 ua = *(const ushort4*)&aggs[t0][k0 + kk];
      ushort4 ub = *(const ushort4*)&aggs[t0 + 1][k0 + kk];
      float a0[4] = {bf2f(ua.x), bf2f(ua.y), bf2f(ua.z), bf2f(ua.w)};
      float a1[4] = {bf2f(ub.x), bf2f(ub.y), bf2f(ub.z), bf2f(ub.w)};
      #pragma unroll
      for (int q = 0; q < 4; ++q) {
        const float* pp = &U.pws[(kk + q) * 132 + o0];
        float4 p0 = *(const float4*)pp;
        float4 p1 = *(const float4*)(pp + 4);
        float av0 = a0[q], av1 = a1[q];
        acc[0][0] += p0.x * av0; acc[0][1] += p0.x * av1;
        acc[1][0] += p0.y * av0; acc[1][1] += p0.y * av1;
        acc[2][0] += p0.z * av0; acc[2][1] += p0.z * av1;
        acc[3][0] += p0.w * av0; acc[3][1] += p0.w * av1;
        acc[4][0] += p1.x * av0; acc[4][1] += p1.x * av1;
        acc[5][0] += p1.y * av0; acc[5][1] += p1.y * av1;
        acc[6][0] += p1.z * av0; acc[6][1] += p1.z * av1;
        acc[7][0] += p1.w * av0; acc[7][1] += p1.w * av1;
      }
    }
  }

  // epilogue
  size_t obase = (((size_t)b * COUT + o0) << 14) + (h << 7) + w0 + t0;
  #pragma unroll
  for (int j = 0; j < 8; ++j) {
    float bias = pb[o0 + j];
    float* op = out + obase + ((size_t)j << 14);
    op[0] = acc[j][0] + bias;
    op[1] = acc[j][1] + bias;
  }
}

extern "C" void kernel_launch(void* const* d_in, const int* in_sizes, int n_in,
                              void* d_out, int out_size, void* d_ws, size_t ws_size,
                              hipStream_t stream) {
  const float* x     = (const float*)d_in[0];
  const float* gw    = (const float*)d_in[1];
  const float* gb    = (const float*)d_in[2];
  const float* theta = (const float*)d_in[3];
  const float* rsu   = (const float*)d_in[4];
  const float* rss   = (const float*)d_in[5];
  const float* pw    = (const float*)d_in[6];
  const float* pb    = (const float*)d_in[7];
  float* outp = (float*)d_out;

  float* wkern = (float*)d_ws;           // 64 floats reserved
  float* wmu   = wkern + 64;             // B*R*L floats = 2 MB

  k_kern_table<<<1, 64, 0, stream>>>(theta, rsu, rss, wkern);
  k_mu<<<(BB * LL) / 256, 256, 0, stream>>>(x, gw, gb, wmu);
  k_fused<<<BB * HH * NTW, 256, 0, stream>>>(x, wmu, wkern, pw, pb, outp);
}

// Round 2
// 117.410 us; speedup vs baseline: 2.1779x; 2.1779x over previous
//
#include <hip/hip_runtime.h>
#include <math.h>

#define CC 64
#define RR 4
#define HH 128
#define WW 128
#define BB 8
#define LL (HH*WW)
#define COUT 128
#define TILE 32
#define NTW (WW/TILE)
#define AGS 264   // aggs row stride in shorts (=528B = 33*16B -> bandwidth-minimal b128)

typedef __attribute__((ext_vector_type(8))) short short8;
typedef __attribute__((ext_vector_type(4))) float f32x4;

__device__ __forceinline__ unsigned short f2bf(float f) {
  unsigned u = __float_as_uint(f);
  u += 0x7fffu + ((u >> 16) & 1u);
  return (unsigned short)(u >> 16);
}
__device__ __forceinline__ float bf2f(unsigned short h) {
  return __uint_as_float(((unsigned)h) << 16);
}

// --- K0: kern table (36 floats) + pw -> bf16 conversion
__global__ __launch_bounds__(256) void k_pre(const float* __restrict__ theta,
                                             const float* __restrict__ rsu,
                                             const float* __restrict__ rss,
                                             const float* __restrict__ pw,
                                             float* __restrict__ wkern,
                                             unsigned short* __restrict__ pwb) {
  int i = blockIdx.x * 256 + threadIdx.x;
  if (i < COUT * RR * CC) pwb[i] = f2bf(pw[i]);
  if (blockIdx.x == 0 && threadIdx.x < RR * 9) {
    int t = threadIdx.x;
    int r = t / 9, s = t % 9;
    float dy = (float)(s / 3 - 1), dx = (float)(s % 3 - 1);
    float ct = cosf(theta[r]), st = sinf(theta[r]);
    float su = log1pf(expf(rsu[r])) + 1e-4f;
    float sv = log1pf(expf(rss[r])) + 1e-4f;
    float pu = ct * dx + st * dy;
    float ps = -st * dx + ct * dy;
    wkern[t] = expf(-(pu * pu) / (su * su) - (ps * ps) / (sv * sv));
  }
}

// --- K1: mu = softmax_r( x . gate_w + gate_b ), one thread per pixel
__global__ __launch_bounds__(256) void k_mu(const float* __restrict__ x,
                                            const float* __restrict__ gw,
                                            const float* __restrict__ gb,
                                            float* __restrict__ mu) {
  __shared__ float gws[RR * CC];
  int tid = threadIdx.x;
  if (tid < RR * CC) gws[tid] = gw[tid];
  __syncthreads();
  int idx = blockIdx.x * 256 + tid;       // b*L + l
  int b = idx >> 14, l = idx & (LL - 1);
  float lg0 = gb[0], lg1 = gb[1], lg2 = gb[2], lg3 = gb[3];
  const float* xp = x + (((size_t)b * CC) << 14) + l;
  #pragma unroll 8
  for (int c = 0; c < CC; ++c) {
    float xv = xp[(size_t)c << 14];
    lg0 += xv * gws[c];
    lg1 += xv * gws[CC + c];
    lg2 += xv * gws[2 * CC + c];
    lg3 += xv * gws[3 * CC + c];
  }
  float m = fmaxf(fmaxf(lg0, lg1), fmaxf(lg2, lg3));
  float e0 = expf(lg0 - m), e1 = expf(lg1 - m);
  float e2 = expf(lg2 - m), e3 = expf(lg3 - m);
  float inv = 1.0f / (e0 + e1 + e2 + e3);
  float* mp = mu + (((size_t)b * RR) << 14) + l;
  mp[0] = e0 * inv;
  mp[(size_t)1 << 14] = e1 * inv;
  mp[(size_t)2 << 14] = e2 * inv;
  mp[(size_t)3 << 14] = e3 * inv;
}

// --- K2: fused alpha -> agg(bf16) -> MFMA pointwise GEMM
__global__ __launch_bounds__(256) void k_fused(const float* __restrict__ x,
                                               const float* __restrict__ mu,
                                               const float* __restrict__ wkern,
                                               const unsigned short* __restrict__ pwb,
                                               const float* __restrict__ pb,
                                               float* __restrict__ out) {
  __shared__ float xs[CC * 105];            // [c][row*35+col], rows h-1..h+1, cols w0-1..w0+32
  __shared__ float mus[RR * 105];
  __shared__ float alp[36][33];             // [r*9+s][t]
  __shared__ unsigned short aggs[TILE][AGS];// bf16 agg, [pixel t][k = r*64+c]
  __shared__ float kl[36];

  int tid = threadIdx.x;
  int bid = blockIdx.x;
  int b = bid / (HH * NTW);
  int rem = bid % (HH * NTW);
  int h = rem / NTW;
  int w0 = (rem % NTW) * TILE;

  if (tid < 36) kl[tid] = wkern[tid];

  // phase A: stage x and mu neighborhoods (zero-padded)
  for (int i = tid; i < CC * 102; i += 256) {
    int c = i / 102, j = i % 102;
    int rr = j / 34, cc2 = j % 34;
    int row = h - 1 + rr, col = w0 - 1 + cc2;
    float v = 0.0f;
    if ((unsigned)row < HH && (unsigned)col < WW)
      v = x[(((size_t)b * CC + c) << 14) + (row << 7) + col];
    xs[c * 105 + rr * 35 + cc2] = v;
  }
  for (int i = tid; i < RR * 102; i += 256) {
    int r = i / 102, j = i % 102;
    int rr = j / 34, cc2 = j % 34;
    int row = h - 1 + rr, col = w0 - 1 + cc2;
    float v = 0.0f;
    if ((unsigned)row < HH && (unsigned)col < WW)
      v = mu[(((size_t)b * RR + r) << 14) + (row << 7) + col];
    mus[r * 105 + rr * 35 + cc2] = v;
  }
  __syncthreads();

  // phase B: alpha[36] per pixel, normalized over all (r,s)
  if (tid < TILE) {
    int t = tid;
    float a[36], sum = 0.0f;
    #pragma unroll
    for (int r = 0; r < RR; ++r) {
      float mc = mus[r * 105 + 35 + t + 1];   // center mu
      #pragma unroll
      for (int s = 0; s < 9; ++s) {
        float v = mc * mus[r * 105 + (s / 3) * 35 + t + (s % 3)] * kl[r * 9 + s];
        a[r * 9 + s] = v;
        sum += v;
      }
    }
    float inv = 1.0f / fmaxf(sum, 1e-8f);
    #pragma unroll
    for (int j2 = 0; j2 < 36; ++j2) alp[j2][t] = a[j2] * inv;
  }
  __syncthreads();

  // phase C: agg[t][r*64+c] = sum_s alpha[r][s][t] * x[c][nb(t,s)], bf16
  {
    int t = tid >> 3;          // 0..31
    int cg = tid & 7;          // 0..7
    int c0 = cg * 8;
    float acc[4][8];
    #pragma unroll
    for (int r = 0; r < 4; ++r)
      #pragma unroll
      for (int j = 0; j < 8; ++j) acc[r][j] = 0.0f;

    #pragma unroll
    for (int s = 0; s < 9; ++s) {
      int sr = s / 3, sc = s % 3;
      const float* xr = &xs[sr * 35 + t + sc];
      float xv[8];
      #pragma unroll
      for (int j = 0; j < 8; ++j) xv[j] = xr[(c0 + j) * 105];
      float av[4];
      #pragma unroll
      for (int r = 0; r < 4; ++r) av[r] = alp[r * 9 + s][t];
      #pragma unroll
      for (int r = 0; r < 4; ++r)
        #pragma unroll
        for (int j = 0; j < 8; ++j)
          acc[r][j] = fmaf(av[r], xv[j], acc[r][j]);
    }
    #pragma unroll
    for (int r = 0; r < 4; ++r) {
      short8 wv;
      #pragma unroll
      for (int j = 0; j < 8; ++j) wv[j] = (short)f2bf(acc[r][j]);
      *(short8*)&aggs[t][r * 64 + c0] = wv;
    }
  }
  __syncthreads();

  // phase D: out[128][32] = pwb[128][256] @ aggs^T  via mfma_f32_16x16x32_bf16
  {
    int wv = tid >> 6;          // wave 0..3 -> o-rows [wv*32, wv*32+32)
    int lane = tid & 63;
    int lr = lane & 15;         // A: m-row / B: n-col / D: col
    int lq = lane >> 4;         // k-chunk selector
    int o0 = wv * 32;

    f32x4 acc[2][2];
    #pragma unroll
    for (int i = 0; i < 2; ++i)
      #pragma unroll
      for (int j = 0; j < 2; ++j) acc[i][j] = (f32x4){0.f, 0.f, 0.f, 0.f};

    const unsigned short* pA0 = pwb + (o0 + lr) * 256 + lq * 8;
    const unsigned short* pA1 = pA0 + 16 * 256;

    #pragma unroll
    for (int ks = 0; ks < 8; ++ks) {
      short8 a0 = *(const short8*)(pA0 + ks * 32);
      short8 a1 = *(const short8*)(pA1 + ks * 32);
      short8 b0 = *(const short8*)&aggs[lr][ks * 32 + lq * 8];
      short8 b1 = *(const short8*)&aggs[16 + lr][ks * 32 + lq * 8];
      acc[0][0] = __builtin_amdgcn_mfma_f32_16x16x32_bf16(a0, b0, acc[0][0], 0, 0, 0);
      acc[0][1] = __builtin_amdgcn_mfma_f32_16x16x32_bf16(a0, b1, acc[0][1], 0, 0, 0);
      acc[1][0] = __builtin_amdgcn_mfma_f32_16x16x32_bf16(a1, b0, acc[1][0], 0, 0, 0);
      acc[1][1] = __builtin_amdgcn_mfma_f32_16x16x32_bf16(a1, b1, acc[1][1], 0, 0, 0);
    }

    // epilogue: D col = t (lane&15), row = o = lq*4 + q
    #pragma unroll
    for (int oi = 0; oi < 2; ++oi) {
      #pragma unroll
      for (int q = 0; q < 4; ++q) {
        int o = o0 + oi * 16 + lq * 4 + q;
        float bias = pb[o];
        size_t base = (((size_t)b * COUT + o) << 14) + (h << 7) + w0;
        out[base + lr]      = acc[oi][0][q] + bias;
        out[base + 16 + lr] = acc[oi][1][q] + bias;
      }
    }
  }
}

extern "C" void kernel_launch(void* const* d_in, const int* in_sizes, int n_in,
                              void* d_out, int out_size, void* d_ws, size_t ws_size,
                              hipStream_t stream) {
  const float* x     = (const float*)d_in[0];
  const float* gw    = (const float*)d_in[1];
  const float* gb    = (const float*)d_in[2];
  const float* theta = (const float*)d_in[3];
  const float* rsu   = (const float*)d_in[4];
  const float* rss   = (const float*)d_in[5];
  const float* pw    = (const float*)d_in[6];
  const float* pb    = (const float*)d_in[7];
  float* outp = (float*)d_out;

  float* wkern = (float*)d_ws;                         // 64 floats
  unsigned short* pwb = (unsigned short*)(wkern + 64); // 32768 bf16 = 64KB
  float* wmu = (float*)(pwb + COUT * RR * CC);         // B*R*L floats

  k_pre<<<128, 256, 0, stream>>>(theta, rsu, rss, pw, wkern, pwb);
  k_mu<<<(BB * LL) / 256, 256, 0, stream>>>(x, gw, gb, wmu);
  k_fused<<<BB * HH * NTW, 256, 0, stream>>>(x, wmu, wkern, pwb, pb, outp);
}

// Round 3
// 80.165 us; speedup vs baseline: 3.1897x; 1.4646x over previous
//
#include <hip/hip_runtime.h>
#include <math.h>

#define CC 64
#define RR 4
#define HH 128
#define WW 128
#define BB 8
#define COUT 128

typedef __attribute__((ext_vector_type(8))) short short8;
typedef __attribute__((ext_vector_type(4))) float f32x4;
typedef __attribute__((ext_vector_type(2))) float f32x2;

__device__ __forceinline__ unsigned short f2bf(float f) {
  unsigned u = __float_as_uint(f);
  u += 0x7fffu + ((u >> 16) & 1u);
  return (unsigned short)(u >> 16);
}

// --- K0: kern table (36 floats) + pw -> bf16 conversion
__global__ __launch_bounds__(256) void k_pre(const float* __restrict__ theta,
                                             const float* __restrict__ rsu,
                                             const float* __restrict__ rss,
                                             const float* __restrict__ pw,
                                             float* __restrict__ wkern,
                                             unsigned short* __restrict__ pwb) {
  int i = blockIdx.x * 256 + threadIdx.x;
  if (i < COUT * RR * CC) pwb[i] = f2bf(pw[i]);
  if (blockIdx.x == 0 && threadIdx.x < RR * 9) {
    int t = threadIdx.x;
    int r = t / 9, s = t % 9;
    float dy = (float)(s / 3 - 1), dx = (float)(s % 3 - 1);
    float ct = cosf(theta[r]), st = sinf(theta[r]);
    float su = log1pf(expf(rsu[r])) + 1e-4f;
    float sv = log1pf(expf(rss[r])) + 1e-4f;
    float pu = ct * dx + st * dy;
    float ps = -st * dx + ct * dy;
    wkern[t] = expf(-(pu * pu) / (su * su) - (ps * ps) / (sv * sv));
  }
}

// --- K1: fully fused: stage x -> mu -> alpha -> agg(bf16) -> MFMA GEMM
// tile: 2 rows x 32 cols per block; 2048 blocks; 256 threads
__global__ __launch_bounds__(256) void k_fused(const float* __restrict__ x,
                                               const float* __restrict__ gw,
                                               const float* __restrict__ gb,
                                               const float* __restrict__ wkern,
                                               const unsigned short* __restrict__ pwb,
                                               const float* __restrict__ pb,
                                               float* __restrict__ out) {
  __shared__ float xs[CC][4][40];            // rows h0-1..h0+2, cols w0-4..w0+35
  __shared__ float mus[RR][4][40];           // mu halo (cols 3..36 valid)
  __shared__ float alp[36][64];              // raw alpha [r*9+s][px]
  __shared__ float rsum[RR][64];             // per-r alpha partial sums
  __shared__ unsigned short aggs[32][264];   // bf16 agg, [px-in-round][k=r*64+c]

  int tid = threadIdx.x;
  // XCD-aware bijective swizzle: 2048 blocks % 8 == 0; each XCD gets one image
  int raw = blockIdx.x;
  int bid = (raw & 7) * 256 + (raw >> 3);
  int b = bid >> 8;
  int rem = bid & 255;
  int h0 = (rem >> 2) << 1;        // 64 h-tiles of 2 rows
  int w0 = (rem & 3) << 5;         // 4 w-tiles of 32 cols

  // ---- phase A: stage x halo as float4 (pow2 mapping, no div)
  {
    int c4 = tid & 15;             // f4 slot (10 active)
    int pr0 = tid >> 4;            // 0..15
    if (c4 < 10) {
      int gcol = w0 - 4 + (c4 << 2);
      bool colok = (unsigned)gcol < WW;
      #pragma unroll
      for (int k = 0; k < 16; ++k) {
        int pair = (k << 4) + pr0;         // 0..255 = (c,row)
        int c = pair >> 2, row = pair & 3;
        int grow = h0 - 1 + row;
        float4 v = make_float4(0.f, 0.f, 0.f, 0.f);
        if (colok && (unsigned)grow < HH)
          v = *(const float4*)(x + (((size_t)b * CC + c) << 14) + (grow << 7) + gcol);
        *(float4*)&xs[c][row][c4 << 2] = v;
      }
    }
  }
  __syncthreads();

  // ---- phase Mu: softmax gate for the 4x34 halo (fused; gw/gb scalar loads)
  if (tid < 136) {
    int y = tid / 34, cxo = tid % 34;
    int cx = 3 + cxo;
    int grow = h0 - 1 + y, gcol = w0 - 1 + cxo;
    float lg0 = gb[0], lg1 = gb[1], lg2 = gb[2], lg3 = gb[3];
    #pragma unroll 8
    for (int c = 0; c < CC; ++c) {
      float xv = xs[c][y][cx];
      lg0 = fmaf(xv, gw[c], lg0);
      lg1 = fmaf(xv, gw[64 + c], lg1);
      lg2 = fmaf(xv, gw[128 + c], lg2);
      lg3 = fmaf(xv, gw[192 + c], lg3);
    }
    float m = fmaxf(fmaxf(lg0, lg1), fmaxf(lg2, lg3));
    float e0 = expf(lg0 - m), e1 = expf(lg1 - m);
    float e2 = expf(lg2 - m), e3 = expf(lg3 - m);
    float inv = 1.0f / (e0 + e1 + e2 + e3);
    if (!((unsigned)grow < HH && (unsigned)gcol < WW)) inv = 0.0f;  // zero-pad mu
    mus[0][y][cx] = e0 * inv;
    mus[1][y][cx] = e1 * inv;
    mus[2][y][cx] = e2 * inv;
    mus[3][y][cx] = e3 * inv;
  }
  __syncthreads();

  // ---- phase B: raw alpha per (px, r); 256 threads = 64 px x 4 r
  {
    int t = tid & 63, r = tid >> 6;          // r wave-uniform
    int prow = t >> 5, pcol = t & 31;
    float mc = mus[r][prow + 1][pcol + 4];   // center mu
    float sum = 0.f;
    #pragma unroll
    for (int s = 0; s < 9; ++s) {
      int sr = s / 3, sc = s % 3;
      float a = mc * mus[r][prow + sr][pcol + 3 + sc] * wkern[r * 9 + s];
      alp[r * 9 + s][t] = a;
      sum += a;
    }
    rsum[r][t] = sum;
  }
  __syncthreads();

  int lane = tid & 63;
  int wv = tid >> 6;
  int lr = lane & 15, lq = lane >> 4;
  int o0 = wv << 5;

  #pragma unroll
  for (int p = 0; p < 2; ++p) {
    // ---- phase C: agg (deferred normalization), bf16 pack into LDS
    {
      int t = tid & 31, cg = tid >> 5, c0 = cg << 3;   // lanes 0..31 = t -> no bank conflict
      int px = (p << 5) + t;
      float inv = 1.0f / fmaxf(rsum[0][px] + rsum[1][px] + rsum[2][px] + rsum[3][px], 1e-8f);
      f32x2 cacc[4][4];
      #pragma unroll
      for (int r = 0; r < 4; ++r)
        #pragma unroll
        for (int j = 0; j < 4; ++j) cacc[r][j] = (f32x2){0.f, 0.f};

      #pragma unroll
      for (int s = 0; s < 9; ++s) {
        int sr = s / 3, sc = s % 3;
        f32x2 xv[4];
        #pragma unroll
        for (int j = 0; j < 4; ++j) {
          xv[j][0] = xs[c0 + 2 * j][p + sr][t + 3 + sc];
          xv[j][1] = xs[c0 + 2 * j + 1][p + sr][t + 3 + sc];
        }
        #pragma unroll
        for (int r = 0; r < 4; ++r) {
          float av = alp[r * 9 + s][px];
          f32x2 av2 = {av, av};
          #pragma unroll
          for (int j = 0; j < 4; ++j) cacc[r][j] += av2 * xv[j];
        }
      }
      #pragma unroll
      for (int r = 0; r < 4; ++r) {
        short8 wvv;
        #pragma unroll
        for (int j = 0; j < 4; ++j) {
          wvv[2 * j]     = (short)f2bf(cacc[r][j][0] * inv);
          wvv[2 * j + 1] = (short)f2bf(cacc[r][j][1] * inv);
        }
        *(short8*)&aggs[t][(r << 6) + c0] = wvv;
      }
    }

    // ---- A-fragment loads (global, round-invariant addresses; hide under C)
    short8 a0r[8], a1r[8];
    {
      const unsigned short* pA = pwb + ((o0 + lr) << 8) + (lq << 3);
      #pragma unroll
      for (int ks = 0; ks < 8; ++ks) {
        a0r[ks] = *(const short8*)(pA + (ks << 5));
        a1r[ks] = *(const short8*)(pA + 4096 + (ks << 5));
      }
    }
    __syncthreads();

    // ---- phase D: out[128][32] = pwb @ aggs^T via mfma 16x16x32 bf16
    f32x4 dacc[2][2];
    #pragma unroll
    for (int i = 0; i < 2; ++i)
      #pragma unroll
      for (int j = 0; j < 2; ++j) dacc[i][j] = (f32x4){0.f, 0.f, 0.f, 0.f};

    #pragma unroll
    for (int ks = 0; ks < 8; ++ks) {
      short8 b0 = *(const short8*)&aggs[lr][(ks << 5) + (lq << 3)];
      short8 b1 = *(const short8*)&aggs[16 + lr][(ks << 5) + (lq << 3)];
      dacc[0][0] = __builtin_amdgcn_mfma_f32_16x16x32_bf16(a0r[ks], b0, dacc[0][0], 0, 0, 0);
      dacc[0][1] = __builtin_amdgcn_mfma_f32_16x16x32_bf16(a0r[ks], b1, dacc[0][1], 0, 0, 0);
      dacc[1][0] = __builtin_amdgcn_mfma_f32_16x16x32_bf16(a1r[ks], b0, dacc[1][0], 0, 0, 0);
      dacc[1][1] = __builtin_amdgcn_mfma_f32_16x16x32_bf16(a1r[ks], b1, dacc[1][1], 0, 0, 0);
    }

    // epilogue
    #pragma unroll
    for (int oi = 0; oi < 2; ++oi) {
      #pragma unroll
      for (int q = 0; q < 4; ++q) {
        int o = o0 + (oi << 4) + (lq << 2) + q;
        float bias = pb[o];
        size_t base = (((size_t)b * COUT + o) << 14) + ((h0 + p) << 7) + w0;
        out[base + lr]      = dacc[oi][0][q] + bias;
        out[base + 16 + lr] = dacc[oi][1][q] + bias;
      }
    }
    if (p == 0) __syncthreads();   // protect aggs before next round's phase C
  }
}

extern "C" void kernel_launch(void* const* d_in, const int* in_sizes, int n_in,
                              void* d_out, int out_size, void* d_ws, size_t ws_size,
                              hipStream_t stream) {
  const float* x     = (const float*)d_in[0];
  const float* gw    = (const float*)d_in[1];
  const float* gb    = (const float*)d_in[2];
  const float* theta = (const float*)d_in[3];
  const float* rsu   = (const float*)d_in[4];
  const float* rss   = (const float*)d_in[5];
  const float* pw    = (const float*)d_in[6];
  const float* pb    = (const float*)d_in[7];
  float* outp = (float*)d_out;

  float* wkern = (float*)d_ws;                         // 64 floats
  unsigned short* pwb = (unsigned short*)(wkern + 64); // 32768 bf16

  k_pre<<<128, 256, 0, stream>>>(theta, rsu, rss, pw, wkern, pwb);
  k_fused<<<BB * (HH / 2) * (WW / 32), 256, 0, stream>>>(x, gw, gb, wkern, pwb, pb, outp);
}

// Round 4
// 60.272 us; speedup vs baseline: 4.2426x; 1.3301x over previous
//
#include <hip/hip_runtime.h>
#include <math.h>

#define CC 64
#define RR 4
#define HH 128
#define WW 128
#define BB 8
#define COUT 128
#define XCH 164   // xs channel stride in ushorts (328B = 82 dw ≡ 18 banks -> kills 4-way aliasing)

typedef __attribute__((ext_vector_type(8))) short short8;
typedef __attribute__((ext_vector_type(4))) float f32x4;
typedef __attribute__((ext_vector_type(2))) float f32x2;

__device__ __forceinline__ unsigned short f2bf(float f) {
  unsigned u = __float_as_uint(f);
  u += 0x7fffu + ((u >> 16) & 1u);
  return (unsigned short)(u >> 16);
}
__device__ __forceinline__ float bf2f(unsigned short h) {
  return __uint_as_float(((unsigned)h) << 16);
}

// --- K0: kern table (36 floats) + pw -> bf16 conversion
__global__ __launch_bounds__(256) void k_pre(const float* __restrict__ theta,
                                             const float* __restrict__ rsu,
                                             const float* __restrict__ rss,
                                             const float* __restrict__ pw,
                                             float* __restrict__ wkern,
                                             unsigned short* __restrict__ pwb) {
  int i = blockIdx.x * 256 + threadIdx.x;
  if (i < COUT * RR * CC) pwb[i] = f2bf(pw[i]);
  if (blockIdx.x == 0 && threadIdx.x < RR * 9) {
    int t = threadIdx.x;
    int r = t / 9, s = t % 9;
    float dy = (float)(s / 3 - 1), dx = (float)(s % 3 - 1);
    float ct = cosf(theta[r]), st = sinf(theta[r]);
    float su = log1pf(expf(rsu[r])) + 1e-4f;
    float sv = log1pf(expf(rss[r])) + 1e-4f;
    float pu = ct * dx + st * dy;
    float ps = -st * dx + ct * dy;
    wkern[t] = expf(-(pu * pu) / (su * su) - (ps * ps) / (sv * sv));
  }
}

// --- K1: fully fused: stage x(bf16) -> mu -> alpha -> agg(bf16) -> MFMA GEMM
// tile: 2 rows x 32 cols per block; 2048 blocks; 256 threads; 3 blocks/CU
__global__ __launch_bounds__(256, 3) void k_fused(const float* __restrict__ x,
                                                  const float* __restrict__ gw,
                                                  const float* __restrict__ gb,
                                                  const float* __restrict__ wkern,
                                                  const unsigned short* __restrict__ pwb,
                                                  const float* __restrict__ pb,
                                                  float* __restrict__ out) {
  __shared__ unsigned short xs[CC][XCH];     // bf16 x halo: [c][row*40+col], rows h0-1..h0+2, cols w0-4..w0+35
  __shared__ float mus[RR][4][40];           // mu halo (cols 3..36 valid)
  __shared__ float alp[36][64];              // raw alpha [r*9+s][px]
  __shared__ float rsum[RR][64];             // per-r alpha partial sums
  __shared__ unsigned short aggs[32][264];   // bf16 agg, [px-in-round][k=r*64+c]

  int tid = threadIdx.x;
  // XCD-aware bijective swizzle: 2048 % 8 == 0; each XCD gets one image
  int raw = blockIdx.x;
  int bid = (raw & 7) * 256 + (raw >> 3);
  int b = bid >> 8;
  int rem = bid & 255;
  int h0 = (rem >> 2) << 1;        // 64 h-tiles of 2 rows
  int w0 = (rem & 3) << 5;         // 4 w-tiles of 32 cols

  // ---- phase A: stage x halo as float4 -> bf16x4 ds_write_b64
  {
    int c4 = tid & 15;             // f4 slot (10 active)
    int pr0 = tid >> 4;            // 0..15
    if (c4 < 10) {
      int gcol = w0 - 4 + (c4 << 2);
      bool colok = (unsigned)gcol < WW;
      #pragma unroll
      for (int k = 0; k < 16; ++k) {
        int pair = (k << 4) + pr0;         // 0..255 = (c,row)
        int c = pair >> 2, row = pair & 3;
        int grow = h0 - 1 + row;
        float4 v = make_float4(0.f, 0.f, 0.f, 0.f);
        if (colok && (unsigned)grow < HH)
          v = *(const float4*)(x + (((size_t)b * CC + c) << 14) + (grow << 7) + gcol);
        ushort4 uv;
        uv.x = f2bf(v.x); uv.y = f2bf(v.y); uv.z = f2bf(v.z); uv.w = f2bf(v.w);
        *(ushort4*)&xs[c][row * 40 + (c4 << 2)] = uv;
      }
    }
  }
  __syncthreads();

  // ---- phase Mu: softmax gate for the 4x34 halo (fused)
  if (tid < 136) {
    int y = tid / 34, cxo = tid % 34;
    int cx = 3 + cxo;
    int grow = h0 - 1 + y, gcol = w0 - 1 + cxo;
    float lg0 = gb[0], lg1 = gb[1], lg2 = gb[2], lg3 = gb[3];
    #pragma unroll 8
    for (int c = 0; c < CC; ++c) {
      float xv = bf2f(xs[c][y * 40 + cx]);
      lg0 = fmaf(xv, gw[c], lg0);
      lg1 = fmaf(xv, gw[64 + c], lg1);
      lg2 = fmaf(xv, gw[128 + c], lg2);
      lg3 = fmaf(xv, gw[192 + c], lg3);
    }
    float m = fmaxf(fmaxf(lg0, lg1), fmaxf(lg2, lg3));
    float e0 = expf(lg0 - m), e1 = expf(lg1 - m);
    float e2 = expf(lg2 - m), e3 = expf(lg3 - m);
    float inv = 1.0f / (e0 + e1 + e2 + e3);
    if (!((unsigned)grow < HH && (unsigned)gcol < WW)) inv = 0.0f;  // zero-pad mu
    mus[0][y][cx] = e0 * inv;
    mus[1][y][cx] = e1 * inv;
    mus[2][y][cx] = e2 * inv;
    mus[3][y][cx] = e3 * inv;
  }
  __syncthreads();

  // ---- phase B: raw alpha per (px, r); 256 threads = 64 px x 4 r
  {
    int t = tid & 63, r = tid >> 6;          // r wave-uniform
    int prow = t >> 5, pcol = t & 31;
    float mc = mus[r][prow + 1][pcol + 4];   // center mu
    float sum = 0.f;
    #pragma unroll
    for (int s = 0; s < 9; ++s) {
      int sr = s / 3, sc = s % 3;
      float a = mc * mus[r][prow + sr][pcol + 3 + sc] * wkern[r * 9 + s];
      alp[r * 9 + s][t] = a;
      sum += a;
    }
    rsum[r][t] = sum;
  }

  int lane = tid & 63;
  int wv = tid >> 6;
  int lr = lane & 15, lq = lane >> 4;
  int o0 = wv << 5;

  // ---- A-fragments (p-invariant): load once, hold in regs
  short8 a0r[8], a1r[8];
  {
    const unsigned short* pA = pwb + ((o0 + lr) << 8) + (lq << 3);
    #pragma unroll
    for (int ks = 0; ks < 8; ++ks) {
      a0r[ks] = *(const short8*)(pA + (ks << 5));
      a1r[ks] = *(const short8*)(pA + 4096 + (ks << 5));
    }
  }
  __syncthreads();

  #pragma unroll
  for (int p = 0; p < 2; ++p) {
    // ---- phase C: agg (deferred normalization), bf16 pack into LDS
    {
      int t = tid & 31, cg = tid >> 5, c0 = cg << 3;
      int px = (p << 5) + t;
      float inv = 1.0f / fmaxf(rsum[0][px] + rsum[1][px] + rsum[2][px] + rsum[3][px], 1e-8f);
      f32x2 cacc[4][4];
      #pragma unroll
      for (int r = 0; r < 4; ++r)
        #pragma unroll
        for (int j = 0; j < 4; ++j) cacc[r][j] = (f32x2){0.f, 0.f};

      #pragma unroll
      for (int s = 0; s < 9; ++s) {
        int sr = s / 3, sc = s % 3;
        int xo = (p + sr) * 40 + t + 3 + sc;
        f32x2 xv[4];
        #pragma unroll
        for (int j = 0; j < 4; ++j) {
          xv[j][0] = bf2f(xs[c0 + 2 * j][xo]);
          xv[j][1] = bf2f(xs[c0 + 2 * j + 1][xo]);
        }
        #pragma unroll
        for (int r = 0; r < 4; ++r) {
          float av = alp[r * 9 + s][px];
          f32x2 av2 = {av, av};
          #pragma unroll
          for (int j = 0; j < 4; ++j) cacc[r][j] += av2 * xv[j];
        }
      }
      #pragma unroll
      for (int r = 0; r < 4; ++r) {
        short8 wvv;
        #pragma unroll
        for (int j = 0; j < 4; ++j) {
          wvv[2 * j]     = (short)f2bf(cacc[r][j][0] * inv);
          wvv[2 * j + 1] = (short)f2bf(cacc[r][j][1] * inv);
        }
        *(short8*)&aggs[t][(r << 6) + c0] = wvv;
      }
    }
    __syncthreads();

    // ---- phase D: out[128][32] = pwb @ aggs^T via mfma 16x16x32 bf16
    f32x4 dacc[2][2];
    #pragma unroll
    for (int i = 0; i < 2; ++i)
      #pragma unroll
      for (int j = 0; j < 2; ++j) dacc[i][j] = (f32x4){0.f, 0.f, 0.f, 0.f};

    #pragma unroll
    for (int ks = 0; ks < 8; ++ks) {
      short8 b0 = *(const short8*)&aggs[lr][(ks << 5) + (lq << 3)];
      short8 b1 = *(const short8*)&aggs[16 + lr][(ks << 5) + (lq << 3)];
      dacc[0][0] = __builtin_amdgcn_mfma_f32_16x16x32_bf16(a0r[ks], b0, dacc[0][0], 0, 0, 0);
      dacc[0][1] = __builtin_amdgcn_mfma_f32_16x16x32_bf16(a0r[ks], b1, dacc[0][1], 0, 0, 0);
      dacc[1][0] = __builtin_amdgcn_mfma_f32_16x16x32_bf16(a1r[ks], b0, dacc[1][0], 0, 0, 0);
      dacc[1][1] = __builtin_amdgcn_mfma_f32_16x16x32_bf16(a1r[ks], b1, dacc[1][1], 0, 0, 0);
    }

    // epilogue
    #pragma unroll
    for (int oi = 0; oi < 2; ++oi) {
      #pragma unroll
      for (int q = 0; q < 4; ++q) {
        int o = o0 + (oi << 4) + (lq << 2) + q;
        float bias = pb[o];
        size_t base = (((size_t)b * COUT + o) << 14) + ((h0 + p) << 7) + w0;
        out[base + lr]      = dacc[oi][0][q] + bias;
        out[base + 16 + lr] = dacc[oi][1][q] + bias;
      }
    }
    if (p == 0) __syncthreads();   // protect aggs before next round's phase C
  }
}

extern "C" void kernel_launch(void* const* d_in, const int* in_sizes, int n_in,
                              void* d_out, int out_size, void* d_ws, size_t ws_size,
                              hipStream_t stream) {
  const float* x     = (const float*)d_in[0];
  const float* gw    = (const float*)d_in[1];
  const float* gb    = (const float*)d_in[2];
  const float* theta = (const float*)d_in[3];
  const float* rsu   = (const float*)d_in[4];
  const float* rss   = (const float*)d_in[5];
  const float* pw    = (const float*)d_in[6];
  const float* pb    = (const float*)d_in[7];
  float* outp = (float*)d_out;

  float* wkern = (float*)d_ws;                         // 64 floats
  unsigned short* pwb = (unsigned short*)(wkern + 64); // 32768 bf16

  k_pre<<<128, 256, 0, stream>>>(theta, rsu, rss, pw, wkern, pwb);
  k_fused<<<BB * (HH / 2) * (WW / 32), 256, 0, stream>>>(x, gw, gb, wkern, pwb, pb, outp);
}